// Round 13
// baseline (30.306 us; speedup 1.0000x reference)
//
#include <hip/hip_runtime.h>

#define BB 384   // batch
#define DD 128   // embedding dim
#define NI 3     // number of losses
#define SS 25    // seq len in target
#define APB 4    // anchors per block
#define BPI (BB / APB)         // 96 blocks per i
#define GRIDT (2 * BPI)        // 192: triplet kernel covers i=0,1 only
#define PSTRIDE 128            // padded partial stride per i

// ---------------------------------------------------------------------------
// Kernel 1: per block = (i in {0,1}, 4 consecutive anchors). Anchor rows read
// via BLOCK-UNIFORM pointer -> scalar loads (SGPRs); dot loop is
// v_fma(v,s,v), no LDS traffic. Each thread owns row t (float4 loads).
// Anchor norms free (thread t==a_k publishes own-row bb). Positives compacted
// into dense per-anchor lists. Block pre-sums 4 anchors' (tot,cnt) into one
// partial slot; plain stores, no atomics/fences (kernel-boundary sync).
// i=2 (continuous labels) is handled by the finalize kernel.
// ---------------------------------------------------------------------------
__global__ __launch_bounds__(384) void triplet_kernel(
    const float* __restrict__ vr,          // [NI, BB, DD]
    const int*   __restrict__ label_item,  // [BB]
    float* __restrict__ part_T,            // [2 * PSTRIDE]
    int*   __restrict__ part_C)            // [2 * PSTRIDE]
{
    const int blk  = blockIdx.x;           // 0 .. GRIDT-1
    const int i    = blk / BPI;            // 0 or 1 (uniform, SGPR)
    const int b    = blk % BPI;
    const int a0   = b * APB;
    const int t    = threadIdx.x;          // 0 .. 383
    const int lane = t & 63;
    const int wid  = t >> 6;               // 0 .. 5

    __shared__ float aas[APB];             // ||x_{a_k}||^2
    __shared__ float dp_seg[APB][BB];      // dense positive-distance lists
    __shared__ int   wp[6][APB];           // per-wave positive counts
    __shared__ float rf[6];
    __shared__ int   ri[6];

    // block-uniform anchor base pointer (scalar loads in the dot loop)
    const float4* axp = (const float4*)(vr + ((size_t)i * BB + a0) * DD);

    // classification per anchor (int labels, no LDS)
    bool isPos[APB], isNeg[APB];
    const int li_t = label_item[t];
    #pragma unroll
    for (int k = 0; k < APB; ++k) {
        const int li_a = label_item[a0 + k];   // uniform -> scalar load
        isPos[k] = (li_t == li_a) && (t != a0 + k);
        isNeg[k] = (li_t != li_a);
    }

    // in-wave compaction ranks per anchor
    int rp[APB];
    const unsigned long long lowmask =
        (lane == 0) ? 0ull : (~0ull >> (64 - lane));
    #pragma unroll
    for (int k = 0; k < APB; ++k) {
        const unsigned long long mpk = __ballot(isPos[k]);
        rp[k] = __popcll(mpk & lowmask);
        if (lane == 0) wp[wid][k] = __popcll(mpk);
    }
    __syncthreads();                       // B1: wp visible

    // block-level dense offsets + totals per anchor (registers, no barrier)
    int P[APB], posBase[APB];
    #pragma unroll
    for (int k = 0; k < APB; ++k) {
        P[k] = 0; posBase[k] = 0;
        #pragma unroll
        for (int w = 0; w < 6; ++w) {
            if (w < wid) posBase[k] += wp[w][k];
            P[k] += wp[w][k];
        }
    }
    const int Pany = P[0] + P[1] + P[2] + P[3];
    if (Pany == 0) {                       // generic guard (not expected here)
        if (t == 0) { part_T[i * PSTRIDE + b] = 0.0f; part_C[i * PSTRIDE + b] = 0; }
        return;
    }

    // 4 dots + own-row squared norm; own row float4 (vector), anchors scalar
    const float4* xb = (const float4*)(vr + ((size_t)i * BB + t) * DD);
    float ab0 = 0.0f, ab1 = 0.0f, ab2 = 0.0f, ab3 = 0.0f, bb = 0.0f;
    #pragma unroll 4
    for (int c = 0; c < DD / 4; ++c) {
        const float4 bv  = xb[c];
        const float4 a0v = axp[c];                  // uniform -> SGPRs
        const float4 a1v = axp[(DD / 4) + c];
        const float4 a2v = axp[2 * (DD / 4) + c];
        const float4 a3v = axp[3 * (DD / 4) + c];
        ab0 = fmaf(a0v.x, bv.x, ab0); ab0 = fmaf(a0v.y, bv.y, ab0);
        ab0 = fmaf(a0v.z, bv.z, ab0); ab0 = fmaf(a0v.w, bv.w, ab0);
        ab1 = fmaf(a1v.x, bv.x, ab1); ab1 = fmaf(a1v.y, bv.y, ab1);
        ab1 = fmaf(a1v.z, bv.z, ab1); ab1 = fmaf(a1v.w, bv.w, ab1);
        ab2 = fmaf(a2v.x, bv.x, ab2); ab2 = fmaf(a2v.y, bv.y, ab2);
        ab2 = fmaf(a2v.z, bv.z, ab2); ab2 = fmaf(a2v.w, bv.w, ab2);
        ab3 = fmaf(a3v.x, bv.x, ab3); ab3 = fmaf(a3v.y, bv.y, ab3);
        ab3 = fmaf(a3v.z, bv.z, ab3); ab3 = fmaf(a3v.w, bv.w, ab3);
        bb  = fmaf(bv.x,  bv.x, bb ); bb  = fmaf(bv.y,  bv.y, bb );
        bb  = fmaf(bv.z,  bv.z, bb ); bb  = fmaf(bv.w,  bv.w, bb );
    }
    // anchor a_k IS row a_k: its thread publishes bb as the anchor norm
    if (t >= a0 && t < a0 + APB) aas[t - a0] = bb;
    __syncthreads();                       // B2: aas visible

    // d^2 = 2 - 2*cos (unit-norm rows; approx err ~1e-6 << 0.037 threshold)
    const float invb = rsqrtf(fmaxf(bb, 1e-24f));
    const float ab[APB] = { ab0, ab1, ab2, ab3 };
    float d[APB];
    #pragma unroll
    for (int k = 0; k < APB; ++k) {
        const float inva = rsqrtf(fmaxf(aas[k], 1e-24f));
        const float cosv = ab[k] * (inva * invb);
        d[k] = sqrtf(fmaxf(fmaf(-2.0f, cosv, 2.0f), 0.0f));
        if (isPos[k]) dp_seg[k][posBase[k] + rp[k]] = d[k];
    }
    __syncthreads();                       // B3: dp_seg visible

    // sweep: each negative thread scans the dense positive list per anchor
    float tot = 0.0f;
    int   cnt = 0;
    #pragma unroll
    for (int k = 0; k < APB; ++k) {
        if (isNeg[k]) {
            const float dk = d[k];
            const float* seg = dp_seg[k];
            const int    Pk  = P[k];
            #pragma unroll 4
            for (int p = 0; p < Pk; ++p) {
                const float term = 1.0f - (dk - seg[p]);   // 1 - (an - ap)
                if (term > 0.0f && term < 1.0f) { cnt += 1; tot += term; }
            }
        }
    }
    #pragma unroll
    for (int off = 32; off > 0; off >>= 1) {
        tot += __shfl_down(tot, off, 64);
        cnt += __shfl_down(cnt, off, 64);
    }
    if (lane == 0) { rf[wid] = tot; ri[wid] = cnt; }
    __syncthreads();                       // B4
    if (t == 0) {
        float T = 0.0f; int C = 0;
        #pragma unroll
        for (int w = 0; w < 6; ++w) { T += rf[w]; C += ri[w]; }
        part_T[i * PSTRIDE + b] = T;
        part_C[i * PSTRIDE + b] = C;
    }
}

// ---------------------------------------------------------------------------
// Kernel 2: finalize + the i=2 loss. 384 threads.
//  - thread t computes mean(target[t, :, 2]) -> labs[t] (LDS)
//  - duplicate scan via LDS broadcast reads (all threads read labs[p] at the
//    same p -> bank broadcast); no duplicates (a.s.) => l2 = 0.
//  - guarded block-wide slow path computes l2 exactly if duplicates exist
//    (deterministic, data-dependent, a.s. dead).
//  - meanwhile reduces the i=0,1 partials (waves 0-1 -> l0, waves 2-3 -> l1).
// ---------------------------------------------------------------------------
__global__ __launch_bounds__(384) void finalize_kernel(
    const float* __restrict__ vr,          // [NI, BB, DD]
    const float* __restrict__ target,      // [BB, SS, NI]
    const float* __restrict__ part_T,      // [2 * PSTRIDE]
    const int*   __restrict__ part_C,      // [2 * PSTRIDE]
    float* __restrict__ out)               // [4]
{
    const int t    = threadIdx.x;
    const int lane = t & 63;
    const int wid  = t >> 6;               // 0..5
    const int j    = t >> 7;               // 0..2 (128-thread group)
    const int b2   = t & 127;

    __shared__ float labs[BB];
    __shared__ float rf[6];
    __shared__ int   ri[6];
    __shared__ int   dupFlag;
    __shared__ float norms[BB];            // slow path only
    __shared__ float drow[BB];             // slow path only

    if (t == 0) dupFlag = 0;

    // i=0,1 partial loads (independent; overlap with the mean computation)
    float T = 0.0f; int C = 0;
    if (j < 2 && b2 < BPI) { T = part_T[j * PSTRIDE + b2]; C = part_C[j * PSTRIDE + b2]; }

    // mean of target[t, :, 2]
    float m = 0.0f;
    const float* tp = target + (size_t)t * (SS * NI) + 2;
    #pragma unroll
    for (int s = 0; s < SS; ++s) m += tp[s * NI];
    m *= (1.0f / (float)SS);
    labs[t] = m;
    __syncthreads();                       // labs + dupFlag init visible

    // duplicate scan (LDS broadcast: all threads read the same labs[p])
    bool dup = false;
    for (int p = 0; p < BB; ++p) dup |= (labs[p] == m) && (p != t);
    if (dup) dupFlag = 1;                  // benign same-value race

    // reduce i=0,1 partials
    #pragma unroll
    for (int off = 32; off > 0; off >>= 1) {
        T += __shfl_down(T, off, 64);
        C += __shfl_down(C, off, 64);
    }
    if (lane == 0) { rf[wid] = T; ri[wid] = C; }
    __syncthreads();                       // rf/ri + dupFlag visible

    // ---- i=2 loss: 0 unless duplicate labels exist (slow path, a.s. dead) --
    float l2 = 0.0f;
    if (dupFlag) {
        // own-row squared norm in slice i=2
        const float4* xb = (const float4*)(vr + ((size_t)2 * BB + t) * DD);
        float bb = 0.0f;
        #pragma unroll 4
        for (int c = 0; c < DD / 4; ++c) {
            const float4 bv = xb[c];
            bb = fmaf(bv.x, bv.x, bb); bb = fmaf(bv.y, bv.y, bb);
            bb = fmaf(bv.z, bv.z, bb); bb = fmaf(bv.w, bv.w, bb);
        }
        norms[t] = bb;
        __syncthreads();
        const float invb = rsqrtf(fmaxf(bb, 1e-24f));
        float tot2 = 0.0f; int cnt2 = 0;
        for (int a = 0; a < BB; ++a) {
            const float4* axp = (const float4*)(vr + ((size_t)2 * BB + a) * DD);
            float abx = 0.0f;
            #pragma unroll 4
            for (int c = 0; c < DD / 4; ++c) {
                const float4 bv = xb[c];
                const float4 av = axp[c];
                abx = fmaf(av.x, bv.x, abx); abx = fmaf(av.y, bv.y, abx);
                abx = fmaf(av.z, bv.z, abx); abx = fmaf(av.w, bv.w, abx);
            }
            const float inva = rsqrtf(fmaxf(norms[a], 1e-24f));
            const float cosv = abx * (inva * invb);
            drow[t] = sqrtf(fmaxf(fmaf(-2.0f, cosv, 2.0f), 0.0f));
            __syncthreads();
            const float la = labs[a];
            if (labs[t] != la) {           // t is a negative for anchor a
                const float dn = drow[t];
                for (int p = 0; p < BB; ++p) {
                    if (labs[p] == la && p != a) {
                        const float term = 1.0f - (dn - drow[p]);
                        if (term > 0.0f && term < 1.0f) { cnt2 += 1; tot2 += term; }
                    }
                }
            }
            __syncthreads();
        }
        // block reduce tot2/cnt2
        #pragma unroll
        for (int off = 32; off > 0; off >>= 1) {
            tot2 += __shfl_down(tot2, off, 64);
            cnt2 += __shfl_down(cnt2, off, 64);
        }
        __shared__ float rf2[6]; __shared__ int ri2[6];
        if (lane == 0) { rf2[wid] = tot2; ri2[wid] = cnt2; }
        __syncthreads();
        if (t == 0) {
            float Ts = 0.0f; int Cs = 0;
            #pragma unroll
            for (int w = 0; w < 6; ++w) { Ts += rf2[w]; Cs += ri2[w]; }
            l2 = (Cs > 0) ? (Ts / (float)Cs) : 0.0f;
        }
    }

    if (t == 0) {
        float lsum = 0.0f;
        #pragma unroll
        for (int k = 0; k < 2; ++k) {
            const float Tk = rf[2 * k] + rf[2 * k + 1];
            const int   Ck = ri[2 * k] + ri[2 * k + 1];
            const float lk = (Ck > 0) ? (Tk / (float)Ck) : 0.0f;
            out[1 + k] = lk;
            lsum += lk;
        }
        out[3] = l2;
        out[0] = lsum + l2;
    }
}

extern "C" void kernel_launch(void* const* d_in, const int* in_sizes, int n_in,
                              void* d_out, int out_size, void* d_ws, size_t ws_size,
                              hipStream_t stream) {
    const float* vr         = (const float*)d_in[1];
    const float* target     = (const float*)d_in[2];
    const int*   label_item = (const int*)d_in[4];
    float* out = (float*)d_out;

    float* part_T = (float*)d_ws;                 // 2*PSTRIDE floats
    int*   part_C = (int*)(part_T + 2 * PSTRIDE); // 2*PSTRIDE ints

    triplet_kernel<<<GRIDT, 384, 0, stream>>>(vr, label_item, part_T, part_C);
    finalize_kernel<<<1, 384, 0, stream>>>(vr, target, part_T, part_C, out);
}

// Round 14
// 25.443 us; speedup vs baseline: 1.1911x; 1.1911x over previous
//
#include <hip/hip_runtime.h>

#define BB 384   // batch
#define DD 128   // embedding dim
#define NI 3     // number of losses
#define SS 25    // seq len in target
#define APB 6    // anchors per block -> grid 192 <= 256 CUs (no straggler CUs)
#define BPI (BB / APB)         // 64 blocks per i
#define GRID (NI * BPI)        // 192
#define PSTRIDE 128            // padded partial stride per i
#define NW 6                   // waves per block

// ---------------------------------------------------------------------------
// Kernel 1 (R12 structure, APB=6): per block = (i, 6 consecutive anchors).
// Anchor rows read via BLOCK-UNIFORM pointer -> scalar loads (SGPRs); dot
// loop is v_fma(v,s,v), no LDS traffic. Each thread owns row t (float4
// loads). Anchor norms free (thread t==a_k publishes own-row bb). Positives
// compacted into dense per-anchor lists. Block pre-sums its anchors'
// (tot,cnt) into one partial slot; plain stores, no atomics, no fences.
// ---------------------------------------------------------------------------
__global__ __launch_bounds__(384) void triplet_kernel(
    const float* __restrict__ vr,          // [NI, BB, DD]
    const float* __restrict__ target,      // [BB, SS, NI]
    const int*   __restrict__ label_item,  // [BB]
    float* __restrict__ part_T,            // [NI * PSTRIDE]
    int*   __restrict__ part_C)            // [NI * PSTRIDE]
{
    const int blk  = blockIdx.x;           // 0 .. GRID-1
    const int i    = blk / BPI;            // uniform (SGPR)
    const int b    = blk % BPI;
    const int a0   = b * APB;
    const int t    = threadIdx.x;          // 0 .. 383
    const int lane = t & 63;
    const int wid  = t >> 6;               // 0 .. 5

    __shared__ float aas[APB];             // ||x_{a_k}||^2
    __shared__ float dp_seg[APB][BB];      // dense positive-distance lists
    __shared__ int   wp[NW][APB];          // per-wave positive counts
    __shared__ float labs2[BB];            // i=2 only
    __shared__ float rf[NW];
    __shared__ int   ri[NW];

    // block-uniform anchor base pointer (scalar loads in the dot loop)
    const float4* axp = (const float4*)(vr + ((size_t)i * BB + a0) * DD);

    // classification per anchor
    bool isPos[APB], isNeg[APB];
    if (i < 2) {
        const int li_t = label_item[t];
        #pragma unroll
        for (int k = 0; k < APB; ++k) {
            const int li_a = label_item[a0 + k];   // uniform -> scalar load
            isPos[k] = (li_t == li_a) && (t != a0 + k);
            isNeg[k] = (li_t != li_a);
        }
    } else {
        float m = 0.0f;
        const float* tp = target + (size_t)t * (SS * NI) + 2;
        #pragma unroll
        for (int s = 0; s < SS; ++s) m += tp[s * NI];
        m *= (1.0f / (float)SS);
        labs2[t] = m;
        __syncthreads();
        #pragma unroll
        for (int k = 0; k < APB; ++k) {
            const float la = labs2[a0 + k];
            isPos[k] = (m == la) && (t != a0 + k);
            isNeg[k] = (m != la);
        }
    }

    // in-wave compaction ranks per anchor
    int rp[APB];
    const unsigned long long lowmask =
        (lane == 0) ? 0ull : (~0ull >> (64 - lane));
    #pragma unroll
    for (int k = 0; k < APB; ++k) {
        const unsigned long long mpk = __ballot(isPos[k]);
        rp[k] = __popcll(mpk & lowmask);
        if (lane == 0) wp[wid][k] = __popcll(mpk);
    }
    __syncthreads();                       // B1: wp (and labs2) visible

    // block-level dense offsets + totals per anchor (registers, no barrier)
    int P[APB], posBase[APB];
    int Pany = 0;
    #pragma unroll
    for (int k = 0; k < APB; ++k) {
        P[k] = 0; posBase[k] = 0;
        #pragma unroll
        for (int w = 0; w < NW; ++w) {
            if (w < wid) posBase[k] += wp[w][k];
            P[k] += wp[w][k];
        }
        Pany += P[k];
    }
    if (Pany == 0) {                       // block-uniform (all i=2 blocks a.s.)
        if (t == 0) { part_T[i * PSTRIDE + b] = 0.0f; part_C[i * PSTRIDE + b] = 0; }
        return;
    }

    // 6 dots + own-row squared norm; own row float4 (vector), anchors scalar
    const float4* xb = (const float4*)(vr + ((size_t)i * BB + t) * DD);
    float ab[APB];
    #pragma unroll
    for (int k = 0; k < APB; ++k) ab[k] = 0.0f;
    float bb = 0.0f;
    #pragma unroll 4
    for (int c = 0; c < DD / 4; ++c) {
        const float4 bv = xb[c];
        bb = fmaf(bv.x, bv.x, bb); bb = fmaf(bv.y, bv.y, bb);
        bb = fmaf(bv.z, bv.z, bb); bb = fmaf(bv.w, bv.w, bb);
        #pragma unroll
        for (int k = 0; k < APB; ++k) {
            const float4 av = axp[k * (DD / 4) + c];    // uniform -> SGPRs
            ab[k] = fmaf(av.x, bv.x, ab[k]);
            ab[k] = fmaf(av.y, bv.y, ab[k]);
            ab[k] = fmaf(av.z, bv.z, ab[k]);
            ab[k] = fmaf(av.w, bv.w, ab[k]);
        }
    }
    // anchor a_k IS row a_k: its thread publishes bb as the anchor norm
    if (t >= a0 && t < a0 + APB) aas[t - a0] = bb;
    __syncthreads();                       // B2: aas visible

    // d^2 = 2 - 2*cos (unit-norm rows; approx err ~1e-6 << 0.037 threshold)
    const float invb = rsqrtf(fmaxf(bb, 1e-24f));
    float d[APB];
    #pragma unroll
    for (int k = 0; k < APB; ++k) {
        const float inva = rsqrtf(fmaxf(aas[k], 1e-24f));
        const float cosv = ab[k] * (inva * invb);
        d[k] = sqrtf(fmaxf(fmaf(-2.0f, cosv, 2.0f), 0.0f));
        if (isPos[k]) dp_seg[k][posBase[k] + rp[k]] = d[k];
    }
    __syncthreads();                       // B3: dp_seg visible

    // sweep: each negative thread scans the dense positive list per anchor
    float tot = 0.0f;
    int   cnt = 0;
    #pragma unroll
    for (int k = 0; k < APB; ++k) {
        if (isNeg[k]) {
            const float dk = d[k];
            const float* seg = dp_seg[k];
            const int    Pk  = P[k];
            #pragma unroll 4
            for (int p = 0; p < Pk; ++p) {
                const float term = 1.0f - (dk - seg[p]);   // 1 - (an - ap)
                if (term > 0.0f && term < 1.0f) { cnt += 1; tot += term; }
            }
        }
    }
    #pragma unroll
    for (int off = 32; off > 0; off >>= 1) {
        tot += __shfl_down(tot, off, 64);
        cnt += __shfl_down(cnt, off, 64);
    }
    if (lane == 0) { rf[wid] = tot; ri[wid] = cnt; }
    __syncthreads();                       // B4
    if (t == 0) {
        float T = 0.0f; int C = 0;
        #pragma unroll
        for (int w = 0; w < NW; ++w) { T += rf[w]; C += ri[w]; }
        part_T[i * PSTRIDE + b] = T;
        part_C[i * PSTRIDE + b] = C;
    }
}

// ---------------------------------------------------------------------------
// Kernel 2: 384 threads; 128-thread group per loss. 1 barrier, 4 outputs.
// ---------------------------------------------------------------------------
__global__ __launch_bounds__(384) void finalize_kernel(
    const float* __restrict__ part_T,
    const int*   __restrict__ part_C,
    float* __restrict__ out)
{
    const int t    = threadIdx.x;
    const int lane = t & 63;
    const int wid  = t >> 6;
    const int i    = t >> 7;       // 0..2
    const int b    = t & 127;
    __shared__ float rf[6];
    __shared__ int   ri[6];

    float T = (b < BPI) ? part_T[i * PSTRIDE + b] : 0.0f;
    int   C = (b < BPI) ? part_C[i * PSTRIDE + b] : 0;
    #pragma unroll
    for (int off = 32; off > 0; off >>= 1) {
        T += __shfl_down(T, off, 64);
        C += __shfl_down(C, off, 64);
    }
    if (lane == 0) { rf[wid] = T; ri[wid] = C; }
    __syncthreads();
    if (t == 0) {
        float lsum = 0.0f;
        #pragma unroll
        for (int j = 0; j < NI; ++j) {
            const float Tj = rf[2 * j] + rf[2 * j + 1];
            const int   Cj = ri[2 * j] + ri[2 * j + 1];
            const float lj = (Cj > 0) ? (Tj / (float)Cj) : 0.0f;
            out[1 + j] = lj;
            lsum += lj;
        }
        out[0] = lsum;
    }
}

extern "C" void kernel_launch(void* const* d_in, const int* in_sizes, int n_in,
                              void* d_out, int out_size, void* d_ws, size_t ws_size,
                              hipStream_t stream) {
    const float* vr         = (const float*)d_in[1];
    const float* target     = (const float*)d_in[2];
    const int*   label_item = (const int*)d_in[4];
    float* out = (float*)d_out;

    float* part_T = (float*)d_ws;                  // NI*PSTRIDE floats
    int*   part_C = (int*)(part_T + NI * PSTRIDE); // NI*PSTRIDE ints

    triplet_kernel<<<GRID, 384, 0, stream>>>(vr, target, label_item,
                                             part_T, part_C);
    finalize_kernel<<<1, 384, 0, stream>>>(part_T, part_C, out);
}

// Round 15
// 22.061 us; speedup vs baseline: 1.3737x; 1.1533x over previous
//
#include <hip/hip_runtime.h>

#define BB 384   // batch
#define DD 128   // embedding dim
#define NI 3     // number of losses
#define SS 25    // seq len in target
#define APB 4    // anchors per block — measured optimum (4:21.9 / 6:25.4 / 8:37.4)
#define BPI (BB / APB)         // 96 blocks per i
#define GRID (NI * BPI)        // 288
#define PSTRIDE 128            // padded partial stride per i

// ---------------------------------------------------------------------------
// Kernel 1 (R12-proven best, 21.94us): per block = (i, 4 consecutive anchors).
// Anchor rows read via BLOCK-UNIFORM pointer -> scalar loads (SGPRs); the dot
// loop is v_fma(v,s,v) with no LDS traffic. Each thread owns row t (float4
// loads). Anchor norms free (thread t==a_k publishes own-row bb). Positives
// compacted into dense per-anchor lists. Block pre-sums 4 anchors' (tot,cnt)
// into one partial slot; plain stores, no atomics, no fences (kernel-boundary
// ordering is the only cross-block sync that is cheap on MI355X).
// ---------------------------------------------------------------------------
__global__ __launch_bounds__(384) void triplet_kernel(
    const float* __restrict__ vr,          // [NI, BB, DD]
    const float* __restrict__ target,      // [BB, SS, NI]
    const int*   __restrict__ label_item,  // [BB]
    float* __restrict__ part_T,            // [NI * PSTRIDE]
    int*   __restrict__ part_C)            // [NI * PSTRIDE]
{
    const int blk  = blockIdx.x;           // 0 .. GRID-1
    const int i    = blk / BPI;            // uniform (SGPR)
    const int b    = blk % BPI;
    const int a0   = b * APB;
    const int t    = threadIdx.x;          // 0 .. 383
    const int lane = t & 63;
    const int wid  = t >> 6;               // 0 .. 5

    __shared__ float aas[APB];             // ||x_{a_k}||^2
    __shared__ float dp_seg[APB][BB];      // dense positive-distance lists
    __shared__ int   wp[6][APB];           // per-wave positive counts
    __shared__ float labs2[BB];            // i=2 only
    __shared__ float rf[6];
    __shared__ int   ri[6];

    // block-uniform anchor base pointer (scalar loads in the dot loop)
    const float4* axp = (const float4*)(vr + ((size_t)i * BB + a0) * DD);

    // classification per anchor
    bool isPos[APB], isNeg[APB];
    if (i < 2) {
        const int li_t = label_item[t];
        #pragma unroll
        for (int k = 0; k < APB; ++k) {
            const int li_a = label_item[a0 + k];   // uniform -> scalar load
            isPos[k] = (li_t == li_a) && (t != a0 + k);
            isNeg[k] = (li_t != li_a);
        }
    } else {
        float m = 0.0f;
        const float* tp = target + (size_t)t * (SS * NI) + 2;
        #pragma unroll
        for (int s = 0; s < SS; ++s) m += tp[s * NI];
        m *= (1.0f / (float)SS);
        labs2[t] = m;
        __syncthreads();
        #pragma unroll
        for (int k = 0; k < APB; ++k) {
            const float la = labs2[a0 + k];
            isPos[k] = (m == la) && (t != a0 + k);
            isNeg[k] = (m != la);
        }
    }

    // in-wave compaction ranks per anchor
    int rp[APB];
    const unsigned long long lowmask =
        (lane == 0) ? 0ull : (~0ull >> (64 - lane));
    #pragma unroll
    for (int k = 0; k < APB; ++k) {
        const unsigned long long mpk = __ballot(isPos[k]);
        rp[k] = __popcll(mpk & lowmask);
        if (lane == 0) wp[wid][k] = __popcll(mpk);
    }
    __syncthreads();                       // B1: wp (and labs2) visible

    // block-level dense offsets + totals per anchor (registers, no barrier)
    int P[APB], posBase[APB];
    #pragma unroll
    for (int k = 0; k < APB; ++k) {
        P[k] = 0; posBase[k] = 0;
        #pragma unroll
        for (int w = 0; w < 6; ++w) {
            if (w < wid) posBase[k] += wp[w][k];
            P[k] += wp[w][k];
        }
    }
    const int Pany = P[0] + P[1] + P[2] + P[3];
    if (Pany == 0) {                       // block-uniform (all i=2 blocks a.s.)
        if (t == 0) { part_T[i * PSTRIDE + b] = 0.0f; part_C[i * PSTRIDE + b] = 0; }
        return;
    }

    // 4 dots + own-row squared norm; own row float4 (vector), anchors scalar
    const float4* xb = (const float4*)(vr + ((size_t)i * BB + t) * DD);
    float ab0 = 0.0f, ab1 = 0.0f, ab2 = 0.0f, ab3 = 0.0f, bb = 0.0f;
    #pragma unroll 4
    for (int c = 0; c < DD / 4; ++c) {
        const float4 bv  = xb[c];
        const float4 a0v = axp[c];                  // uniform -> SGPRs
        const float4 a1v = axp[(DD / 4) + c];
        const float4 a2v = axp[2 * (DD / 4) + c];
        const float4 a3v = axp[3 * (DD / 4) + c];
        ab0 = fmaf(a0v.x, bv.x, ab0); ab0 = fmaf(a0v.y, bv.y, ab0);
        ab0 = fmaf(a0v.z, bv.z, ab0); ab0 = fmaf(a0v.w, bv.w, ab0);
        ab1 = fmaf(a1v.x, bv.x, ab1); ab1 = fmaf(a1v.y, bv.y, ab1);
        ab1 = fmaf(a1v.z, bv.z, ab1); ab1 = fmaf(a1v.w, bv.w, ab1);
        ab2 = fmaf(a2v.x, bv.x, ab2); ab2 = fmaf(a2v.y, bv.y, ab2);
        ab2 = fmaf(a2v.z, bv.z, ab2); ab2 = fmaf(a2v.w, bv.w, ab2);
        ab3 = fmaf(a3v.x, bv.x, ab3); ab3 = fmaf(a3v.y, bv.y, ab3);
        ab3 = fmaf(a3v.z, bv.z, ab3); ab3 = fmaf(a3v.w, bv.w, ab3);
        bb  = fmaf(bv.x,  bv.x, bb ); bb  = fmaf(bv.y,  bv.y, bb );
        bb  = fmaf(bv.z,  bv.z, bb ); bb  = fmaf(bv.w,  bv.w, bb );
    }
    // anchor a_k IS row a_k: its thread publishes bb as the anchor norm
    if (t >= a0 && t < a0 + APB) aas[t - a0] = bb;
    __syncthreads();                       // B2: aas visible

    // d^2 = 2 - 2*cos (unit-norm rows; approx err ~1e-6 << 0.037 threshold)
    const float invb = rsqrtf(fmaxf(bb, 1e-24f));
    const float ab[APB] = { ab0, ab1, ab2, ab3 };
    float d[APB];
    #pragma unroll
    for (int k = 0; k < APB; ++k) {
        const float inva = rsqrtf(fmaxf(aas[k], 1e-24f));
        const float cosv = ab[k] * (inva * invb);
        d[k] = sqrtf(fmaxf(fmaf(-2.0f, cosv, 2.0f), 0.0f));
        if (isPos[k]) dp_seg[k][posBase[k] + rp[k]] = d[k];
    }
    __syncthreads();                       // B3: dp_seg visible

    // sweep: each negative thread scans the dense positive list per anchor
    float tot = 0.0f;
    int   cnt = 0;
    #pragma unroll
    for (int k = 0; k < APB; ++k) {
        if (isNeg[k]) {
            const float dk = d[k];
            const float* seg = dp_seg[k];
            const int    Pk  = P[k];
            #pragma unroll 4
            for (int p = 0; p < Pk; ++p) {
                const float term = 1.0f - (dk - seg[p]);   // 1 - (an - ap)
                if (term > 0.0f && term < 1.0f) { cnt += 1; tot += term; }
            }
        }
    }
    #pragma unroll
    for (int off = 32; off > 0; off >>= 1) {
        tot += __shfl_down(tot, off, 64);
        cnt += __shfl_down(cnt, off, 64);
    }
    if (lane == 0) { rf[wid] = tot; ri[wid] = cnt; }
    __syncthreads();                       // B4
    if (t == 0) {
        float T = 0.0f; int C = 0;
        #pragma unroll
        for (int w = 0; w < 6; ++w) { T += rf[w]; C += ri[w]; }
        part_T[i * PSTRIDE + b] = T;
        part_C[i * PSTRIDE + b] = C;
    }
}

// ---------------------------------------------------------------------------
// Kernel 2: 384 threads; 128-thread group per loss. 1 barrier, 4 outputs.
// ---------------------------------------------------------------------------
__global__ __launch_bounds__(384) void finalize_kernel(
    const float* __restrict__ part_T,
    const int*   __restrict__ part_C,
    float* __restrict__ out)
{
    const int t    = threadIdx.x;
    const int lane = t & 63;
    const int wid  = t >> 6;
    const int i    = t >> 7;       // 0..2
    const int b    = t & 127;
    __shared__ float rf[6];
    __shared__ int   ri[6];

    float T = (b < BPI) ? part_T[i * PSTRIDE + b] : 0.0f;
    int   C = (b < BPI) ? part_C[i * PSTRIDE + b] : 0;
    #pragma unroll
    for (int off = 32; off > 0; off >>= 1) {
        T += __shfl_down(T, off, 64);
        C += __shfl_down(C, off, 64);
    }
    if (lane == 0) { rf[wid] = T; ri[wid] = C; }
    __syncthreads();
    if (t == 0) {
        float lsum = 0.0f;
        #pragma unroll
        for (int j = 0; j < NI; ++j) {
            const float Tj = rf[2 * j] + rf[2 * j + 1];
            const int   Cj = ri[2 * j] + ri[2 * j + 1];
            const float lj = (Cj > 0) ? (Tj / (float)Cj) : 0.0f;
            out[1 + j] = lj;
            lsum += lj;
        }
        out[0] = lsum;
    }
}

extern "C" void kernel_launch(void* const* d_in, const int* in_sizes, int n_in,
                              void* d_out, int out_size, void* d_ws, size_t ws_size,
                              hipStream_t stream) {
    const float* vr         = (const float*)d_in[1];
    const float* target     = (const float*)d_in[2];
    const int*   label_item = (const int*)d_in[4];
    float* out = (float*)d_out;

    float* part_T = (float*)d_ws;                  // NI*PSTRIDE floats
    int*   part_C = (int*)(part_T + NI * PSTRIDE); // NI*PSTRIDE ints

    triplet_kernel<<<GRID, 384, 0, stream>>>(vr, target, label_item,
                                             part_T, part_C);
    finalize_kernel<<<1, 384, 0, stream>>>(part_T, part_C, out);
}